// Round 6
// baseline (1882.153 us; speedup 1.0000x reference)
//
#include <hip/hip_runtime.h>

#define NN 500000
#define SH 9
#define NPB 512                          // nodes per bucket (1 << SH)
#define NBUCK ((NN + NPB - 1) / NPB)     // 977
#define PT_TILE 32768                    // edges per partition block
#define SENT (NN << SH)                  // sentinel packed edge: src=NN, nd=0

typedef _Float16 hf4 __attribute__((ext_vector_type(4)));
typedef _Float16 hf2 __attribute__((ext_vector_type(2)));

__device__ __forceinline__ hf4 ld_sc0_hf4(const hf4* p) {
    union { unsigned long long u; hf4 h; } c;
    c.u = __hip_atomic_load((const unsigned long long*)p, __ATOMIC_RELAXED,
                            __HIP_MEMORY_SCOPE_AGENT);
    return c.h;
}
__device__ __forceinline__ hf2 ld_sc0_hf2(const hf2* p) {
    union { unsigned int u; hf2 h; } c;
    c.u = __hip_atomic_load((const unsigned int*)p, __ATOMIC_RELAXED,
                            __HIP_MEMORY_SCOPE_AGENT);
    return c.h;
}

// ============================================================================
// pipeline kernels (same structure as round 4; agg gathers now sc0/L1-bypass)
// ============================================================================

__global__ __launch_bounds__(256) void k_bhist(const int* __restrict__ dst,
                                               int* __restrict__ bcount, int ne) {
    __shared__ int lh[NBUCK];
    for (int i = threadIdx.x; i < NBUCK; i += 256) lh[i] = 0;
    __syncthreads();
    int ne4 = ne >> 2;
    for (int i = blockIdx.x * 256 + threadIdx.x; i < ne4; i += gridDim.x * 256) {
        int4 d = ((const int4*)dst)[i];
        atomicAdd(&lh[d.x >> SH], 1);
        atomicAdd(&lh[d.y >> SH], 1);
        atomicAdd(&lh[d.z >> SH], 1);
        atomicAdd(&lh[d.w >> SH], 1);
    }
    if (blockIdx.x == 0) {
        for (int k = (ne & ~3) + threadIdx.x; k < ne; k += 256)
            atomicAdd(&lh[dst[k] >> SH], 1);
    }
    __syncthreads();
    for (int i = threadIdx.x; i < NBUCK; i += 256)
        if (lh[i]) atomicAdd(&bcount[i], lh[i]);
}

__global__ __launch_bounds__(1024) void k_bscan(const int* __restrict__ bcount,
                                                int* __restrict__ bbase,
                                                int* __restrict__ cur,
                                                hf4* __restrict__ g1,
                                                hf4* __restrict__ g2,
                                                hf2* __restrict__ g3) {
    __shared__ int sh[1024];
    int t = threadIdx.x;
    int v = (t < NBUCK) ? bcount[t] : 0;
    int pc = (v + 7) & ~7;
    sh[t] = pc;
    __syncthreads();
    for (int o = 1; o < 1024; o <<= 1) {
        int a = (t >= o) ? sh[t - o] : 0;
        __syncthreads();
        sh[t] += a;
        __syncthreads();
    }
    if (t < NBUCK) {
        int excl = sh[t] - pc;
        bbase[t] = excl;
        cur[t] = excl;
        if (t == NBUCK - 1) bbase[NBUCK] = sh[t];
    }
    if (t == 1023) {
        hf4 z4; z4.x = z4.y = z4.z = z4.w = (_Float16)0.f;
        hf2 z2; z2.x = z2.y = (_Float16)0.f;
        g1[NN] = z4; g2[NN] = z4; g3[NN] = z2;
    }
}

__global__ __launch_bounds__(256) void k_part(const int* __restrict__ src,
                                              const int* __restrict__ dst,
                                              int* __restrict__ cur,
                                              int* __restrict__ packed, int ne) {
    __shared__ int lhist[NBUCK];
    __shared__ int lcur[NBUCK];
    int tid = threadIdx.x;
    for (int i = tid; i < NBUCK; i += 256) lhist[i] = 0;
    __syncthreads();
    int t0 = blockIdx.x * PT_TILE;
    int t1 = t0 + PT_TILE; if (t1 > ne) t1 = ne;
    for (int e = t0 + tid * 4; e < t1; e += 1024) {
        if (e + 3 < t1) {
            int4 d = *(const int4*)(dst + e);
            atomicAdd(&lhist[d.x >> SH], 1);
            atomicAdd(&lhist[d.y >> SH], 1);
            atomicAdd(&lhist[d.z >> SH], 1);
            atomicAdd(&lhist[d.w >> SH], 1);
        } else {
            for (int k = e; k < t1; ++k) atomicAdd(&lhist[dst[k] >> SH], 1);
        }
    }
    __syncthreads();
    for (int i = tid; i < NBUCK; i += 256) {
        int c = lhist[i];
        lcur[i] = c ? atomicAdd(&cur[i], c) : 0;
    }
    __syncthreads();
    for (int e = t0 + tid * 4; e < t1; e += 1024) {
        if (e + 3 < t1) {
            int4 d = *(const int4*)(dst + e);
            int4 s = *(const int4*)(src + e);
            int b, p;
            b = d.x >> SH; p = atomicAdd(&lcur[b], 1); packed[p] = (s.x << SH) | (d.x & (NPB - 1));
            b = d.y >> SH; p = atomicAdd(&lcur[b], 1); packed[p] = (s.y << SH) | (d.y & (NPB - 1));
            b = d.z >> SH; p = atomicAdd(&lcur[b], 1); packed[p] = (s.z << SH) | (d.z & (NPB - 1));
            b = d.w >> SH; p = atomicAdd(&lcur[b], 1); packed[p] = (s.w << SH) | (d.w & (NPB - 1));
        } else {
            for (int k = e; k < t1; ++k) {
                int dd = dst[k], ss = src[k];
                int b = dd >> SH;
                int p = atomicAdd(&lcur[b], 1);
                packed[p] = (ss << SH) | (dd & (NPB - 1));
            }
        }
    }
}

__global__ __launch_bounds__(1024) void k_pad(const int* __restrict__ cur,
                                              const int* __restrict__ bbase,
                                              int* __restrict__ packed) {
    int t = threadIdx.x;
    if (t < NBUCK) {
        int e = cur[t], e1 = bbase[t + 1];
        for (; e < e1; ++e) packed[e] = SENT;
    }
}

__global__ __launch_bounds__(1024) void k_deg(const int* __restrict__ bbase,
                                              const int* __restrict__ packed,
                                              float* __restrict__ dis) {
    __shared__ int cnt[NPB];
    int tid = threadIdx.x, b = blockIdx.x;
    for (int k = tid; k < NPB; k += 1024) cnt[k] = 0;
    __syncthreads();
    int e0 = bbase[b], e1 = bbase[b + 1];
    for (int e = e0 + (tid << 3); e + 8 <= e1; e += 8192) {
        const int4* pp = (const int4*)(packed + e);
        int4 pa = pp[0], pb = pp[1];
        if (pa.x != SENT) atomicAdd(&cnt[pa.x & (NPB - 1)], 1);
        if (pa.y != SENT) atomicAdd(&cnt[pa.y & (NPB - 1)], 1);
        if (pa.z != SENT) atomicAdd(&cnt[pa.z & (NPB - 1)], 1);
        if (pa.w != SENT) atomicAdd(&cnt[pa.w & (NPB - 1)], 1);
        if (pb.x != SENT) atomicAdd(&cnt[pb.x & (NPB - 1)], 1);
        if (pb.y != SENT) atomicAdd(&cnt[pb.y & (NPB - 1)], 1);
        if (pb.z != SENT) atomicAdd(&cnt[pb.z & (NPB - 1)], 1);
        if (pb.w != SENT) atomicAdd(&cnt[pb.w & (NPB - 1)], 1);
    }
    __syncthreads();
    int i0 = b << SH;
    for (int k = tid; k < NPB; k += 1024) {
        int i = i0 + k;
        if (i < NN) dis[i] = rsqrtf((float)cnt[k] + 1.0f);
    }
}

__global__ __launch_bounds__(256) void k_xw(const float* __restrict__ x,
                                            const float* __restrict__ W1,
                                            const float* __restrict__ dis,
                                            hf4* __restrict__ g, int n) {
    __shared__ float4 sW[128];
    int tid = threadIdx.x;
    if (tid < 128) sW[tid] = ((const float4*)W1)[tid];
    __syncthreads();
    int wave = tid >> 6, lane = tid & 63;
    int row = blockIdx.x * 4 + wave;
    if (row >= n) return;
    float2 xv = ((const float2*)(x + (size_t)row * 128))[lane];
    float4 w0 = sW[2 * lane], w1 = sW[2 * lane + 1];
    float a0 = xv.x * w0.x + xv.y * w1.x;
    float a1 = xv.x * w0.y + xv.y * w1.y;
    float a2 = xv.x * w0.z + xv.y * w1.z;
    float a3 = xv.x * w0.w + xv.y * w1.w;
    for (int off = 32; off; off >>= 1) {
        a0 += __shfl_xor(a0, off);
        a1 += __shfl_xor(a1, off);
        a2 += __shfl_xor(a2, off);
        a3 += __shfl_xor(a3, off);
    }
    if (lane == 0) {
        float dv = dis[row];
        hf4 o;
        o.x = (_Float16)(dv * a0); o.y = (_Float16)(dv * a1);
        o.z = (_Float16)(dv * a2); o.w = (_Float16)(dv * a3);
        g[row] = o;
    }
}

#define ACC4(v, nd)                                   \
    unsafeAtomicAdd(&acc[0][nd], (float)(v).x);       \
    unsafeAtomicAdd(&acc[1][nd], (float)(v).y);       \
    unsafeAtomicAdd(&acc[2][nd], (float)(v).z);       \
    unsafeAtomicAdd(&acc[3][nd], (float)(v).w);

__global__ __launch_bounds__(1024) void k_agg44(const int* __restrict__ bbase,
                                                const int* __restrict__ packed,
                                                const hf4* __restrict__ gin,
                                                const float* __restrict__ dis,
                                                const float* __restrict__ bias,
                                                const float* __restrict__ W,
                                                hf4* __restrict__ gout) {
    __shared__ float acc[4][NPB];
    int tid = threadIdx.x, b = blockIdx.x;
    for (int k = tid; k < NPB; k += 1024) {
        acc[0][k] = 0.f; acc[1][k] = 0.f; acc[2][k] = 0.f; acc[3][k] = 0.f;
    }
    __syncthreads();
    int e0 = bbase[b], e1 = bbase[b + 1];
    for (int e = e0 + (tid << 3); e + 8 <= e1; e += 8192) {
        const int4* pp = (const int4*)(packed + e);
        int4 pa = pp[0], pb = pp[1];
        hf4 v0 = ld_sc0_hf4(gin + ((unsigned)pa.x >> SH));
        hf4 v1 = ld_sc0_hf4(gin + ((unsigned)pa.y >> SH));
        hf4 v2 = ld_sc0_hf4(gin + ((unsigned)pa.z >> SH));
        hf4 v3 = ld_sc0_hf4(gin + ((unsigned)pa.w >> SH));
        hf4 v4 = ld_sc0_hf4(gin + ((unsigned)pb.x >> SH));
        hf4 v5 = ld_sc0_hf4(gin + ((unsigned)pb.y >> SH));
        hf4 v6 = ld_sc0_hf4(gin + ((unsigned)pb.z >> SH));
        hf4 v7 = ld_sc0_hf4(gin + ((unsigned)pb.w >> SH));
        ACC4(v0, pa.x & (NPB - 1)); ACC4(v1, pa.y & (NPB - 1));
        ACC4(v2, pa.z & (NPB - 1)); ACC4(v3, pa.w & (NPB - 1));
        ACC4(v4, pb.x & (NPB - 1)); ACC4(v5, pb.y & (NPB - 1));
        ACC4(v6, pb.z & (NPB - 1)); ACC4(v7, pb.w & (NPB - 1));
    }
    __syncthreads();
    int i0 = b << SH;
    for (int k = tid; k < NPB; k += 1024) {
        int i = i0 + k;
        if (i >= NN) continue;
        float dv = dis[i];
        hf4 gs = gin[i];
        float h0 = tanhf(dv * (acc[0][k] + (float)gs.x) + bias[0]);
        float h1 = tanhf(dv * (acc[1][k] + (float)gs.y) + bias[1]);
        float h2 = tanhf(dv * (acc[2][k] + (float)gs.z) + bias[2]);
        float h3 = tanhf(dv * (acc[3][k] + (float)gs.w) + bias[3]);
        hf4 o;
        o.x = (_Float16)(dv * (h0 * W[0] + h1 * W[4] + h2 * W[8]  + h3 * W[12]));
        o.y = (_Float16)(dv * (h0 * W[1] + h1 * W[5] + h2 * W[9]  + h3 * W[13]));
        o.z = (_Float16)(dv * (h0 * W[2] + h1 * W[6] + h2 * W[10] + h3 * W[14]));
        o.w = (_Float16)(dv * (h0 * W[3] + h1 * W[7] + h2 * W[11] + h3 * W[15]));
        gout[i] = o;
    }
}

__global__ __launch_bounds__(1024) void k_agg42(const int* __restrict__ bbase,
                                                const int* __restrict__ packed,
                                                const hf4* __restrict__ gin,
                                                const float* __restrict__ dis,
                                                const float* __restrict__ bias,
                                                const float* __restrict__ W,
                                                hf2* __restrict__ gout) {
    __shared__ float acc[4][NPB];
    int tid = threadIdx.x, b = blockIdx.x;
    for (int k = tid; k < NPB; k += 1024) {
        acc[0][k] = 0.f; acc[1][k] = 0.f; acc[2][k] = 0.f; acc[3][k] = 0.f;
    }
    __syncthreads();
    int e0 = bbase[b], e1 = bbase[b + 1];
    for (int e = e0 + (tid << 3); e + 8 <= e1; e += 8192) {
        const int4* pp = (const int4*)(packed + e);
        int4 pa = pp[0], pb = pp[1];
        hf4 v0 = ld_sc0_hf4(gin + ((unsigned)pa.x >> SH));
        hf4 v1 = ld_sc0_hf4(gin + ((unsigned)pa.y >> SH));
        hf4 v2 = ld_sc0_hf4(gin + ((unsigned)pa.z >> SH));
        hf4 v3 = ld_sc0_hf4(gin + ((unsigned)pa.w >> SH));
        hf4 v4 = ld_sc0_hf4(gin + ((unsigned)pb.x >> SH));
        hf4 v5 = ld_sc0_hf4(gin + ((unsigned)pb.y >> SH));
        hf4 v6 = ld_sc0_hf4(gin + ((unsigned)pb.z >> SH));
        hf4 v7 = ld_sc0_hf4(gin + ((unsigned)pb.w >> SH));
        ACC4(v0, pa.x & (NPB - 1)); ACC4(v1, pa.y & (NPB - 1));
        ACC4(v2, pa.z & (NPB - 1)); ACC4(v3, pa.w & (NPB - 1));
        ACC4(v4, pb.x & (NPB - 1)); ACC4(v5, pb.y & (NPB - 1));
        ACC4(v6, pb.z & (NPB - 1)); ACC4(v7, pb.w & (NPB - 1));
    }
    __syncthreads();
    int i0 = b << SH;
    for (int k = tid; k < NPB; k += 1024) {
        int i = i0 + k;
        if (i >= NN) continue;
        float dv = dis[i];
        hf4 gs = gin[i];
        float h0 = tanhf(dv * (acc[0][k] + (float)gs.x) + bias[0]);
        float h1 = tanhf(dv * (acc[1][k] + (float)gs.y) + bias[1]);
        float h2 = tanhf(dv * (acc[2][k] + (float)gs.z) + bias[2]);
        float h3 = tanhf(dv * (acc[3][k] + (float)gs.w) + bias[3]);
        hf2 o;
        o.x = (_Float16)(dv * (h0 * W[0] + h1 * W[2] + h2 * W[4] + h3 * W[6]));
        o.y = (_Float16)(dv * (h0 * W[1] + h1 * W[3] + h2 * W[5] + h3 * W[7]));
        gout[i] = o;
    }
}

__global__ __launch_bounds__(1024) void k_agg2out(const int* __restrict__ bbase,
                                                  const int* __restrict__ packed,
                                                  const hf2* __restrict__ gin,
                                                  const float* __restrict__ dis,
                                                  const float* __restrict__ b3,
                                                  const float* __restrict__ Wc,
                                                  const float* __restrict__ bc,
                                                  float4* __restrict__ out,
                                                  float2* __restrict__ hout) {
    __shared__ float acc[2][NPB];
    int tid = threadIdx.x, b = blockIdx.x;
    for (int k = tid; k < NPB; k += 1024) { acc[0][k] = 0.f; acc[1][k] = 0.f; }
    __syncthreads();
    int e0 = bbase[b], e1 = bbase[b + 1];
    for (int e = e0 + (tid << 3); e + 8 <= e1; e += 8192) {
        const int4* pp = (const int4*)(packed + e);
        int4 pa = pp[0], pb = pp[1];
        hf2 v0 = ld_sc0_hf2(gin + ((unsigned)pa.x >> SH));
        hf2 v1 = ld_sc0_hf2(gin + ((unsigned)pa.y >> SH));
        hf2 v2 = ld_sc0_hf2(gin + ((unsigned)pa.z >> SH));
        hf2 v3 = ld_sc0_hf2(gin + ((unsigned)pa.w >> SH));
        hf2 v4 = ld_sc0_hf2(gin + ((unsigned)pb.x >> SH));
        hf2 v5 = ld_sc0_hf2(gin + ((unsigned)pb.y >> SH));
        hf2 v6 = ld_sc0_hf2(gin + ((unsigned)pb.z >> SH));
        hf2 v7 = ld_sc0_hf2(gin + ((unsigned)pb.w >> SH));
        int n0, n1;
        n0 = pa.x & (NPB - 1); unsafeAtomicAdd(&acc[0][n0], (float)v0.x); unsafeAtomicAdd(&acc[1][n0], (float)v0.y);
        n1 = pa.y & (NPB - 1); unsafeAtomicAdd(&acc[0][n1], (float)v1.x); unsafeAtomicAdd(&acc[1][n1], (float)v1.y);
        n0 = pa.z & (NPB - 1); unsafeAtomicAdd(&acc[0][n0], (float)v2.x); unsafeAtomicAdd(&acc[1][n0], (float)v2.y);
        n1 = pa.w & (NPB - 1); unsafeAtomicAdd(&acc[0][n1], (float)v3.x); unsafeAtomicAdd(&acc[1][n1], (float)v3.y);
        n0 = pb.x & (NPB - 1); unsafeAtomicAdd(&acc[0][n0], (float)v4.x); unsafeAtomicAdd(&acc[1][n0], (float)v4.y);
        n1 = pb.y & (NPB - 1); unsafeAtomicAdd(&acc[0][n1], (float)v5.x); unsafeAtomicAdd(&acc[1][n1], (float)v5.y);
        n0 = pb.z & (NPB - 1); unsafeAtomicAdd(&acc[0][n0], (float)v6.x); unsafeAtomicAdd(&acc[1][n0], (float)v6.y);
        n1 = pb.w & (NPB - 1); unsafeAtomicAdd(&acc[0][n1], (float)v7.x); unsafeAtomicAdd(&acc[1][n1], (float)v7.y);
    }
    __syncthreads();
    int i0 = b << SH;
    for (int k = tid; k < NPB; k += 1024) {
        int i = i0 + k;
        if (i >= NN) continue;
        float dv = dis[i];
        hf2 gs = gin[i];
        float h0 = tanhf(dv * (acc[0][k] + (float)gs.x) + b3[0]);
        float h1 = tanhf(dv * (acc[1][k] + (float)gs.y) + b3[1]);
        float4 o;
        o.x = h0 * Wc[0] + h1 * Wc[4] + bc[0];
        o.y = h0 * Wc[1] + h1 * Wc[5] + bc[1];
        o.z = h0 * Wc[2] + h1 * Wc[6] + bc[2];
        o.w = h0 * Wc[3] + h1 * Wc[7] + bc[3];
        out[i] = o;
        hout[i] = make_float2(h0, h1);
    }
}

// ============================================================================
// ABLATION PROBES (write only to scratch; run after the real pipeline)
// ============================================================================

// gather-only: isolates the random gather. MODE=0 plain loads, MODE=1 sc0.
template <int MODE>
__global__ __launch_bounds__(1024) void ab_gather(const int* __restrict__ bbase,
                                                  const int* __restrict__ packed,
                                                  const hf4* __restrict__ gin,
                                                  float* __restrict__ dummy) {
    int tid = threadIdx.x, b = blockIdx.x;
    int e0 = bbase[b], e1 = bbase[b + 1];
    float s = 0.f;
    for (int e = e0 + (tid << 3); e + 8 <= e1; e += 8192) {
        const int4* pp = (const int4*)(packed + e);
        int4 pa = pp[0], pb = pp[1];
        hf4 v0, v1, v2, v3, v4, v5, v6, v7;
        if (MODE) {
            v0 = ld_sc0_hf4(gin + ((unsigned)pa.x >> SH));
            v1 = ld_sc0_hf4(gin + ((unsigned)pa.y >> SH));
            v2 = ld_sc0_hf4(gin + ((unsigned)pa.z >> SH));
            v3 = ld_sc0_hf4(gin + ((unsigned)pa.w >> SH));
            v4 = ld_sc0_hf4(gin + ((unsigned)pb.x >> SH));
            v5 = ld_sc0_hf4(gin + ((unsigned)pb.y >> SH));
            v6 = ld_sc0_hf4(gin + ((unsigned)pb.z >> SH));
            v7 = ld_sc0_hf4(gin + ((unsigned)pb.w >> SH));
        } else {
            v0 = gin[(unsigned)pa.x >> SH];
            v1 = gin[(unsigned)pa.y >> SH];
            v2 = gin[(unsigned)pa.z >> SH];
            v3 = gin[(unsigned)pa.w >> SH];
            v4 = gin[(unsigned)pb.x >> SH];
            v5 = gin[(unsigned)pb.y >> SH];
            v6 = gin[(unsigned)pb.z >> SH];
            v7 = gin[(unsigned)pb.w >> SH];
        }
        s += (float)v0.x + (float)v1.x + (float)v2.x + (float)v3.x
           + (float)v4.x + (float)v5.x + (float)v6.x + (float)v7.x
           + (float)v0.w + (float)v7.w;
    }
    // keep all loads live in every thread; condition can never be true
    if (s + (float)tid == -987654.25f) dummy[b & 255] = s;
}

// LDS-only: coalesced loads (512KB window, L2-resident) + full LDS atomic traffic
__global__ __launch_bounds__(1024) void ab_lds(const int* __restrict__ bbase,
                                               const int* __restrict__ packed,
                                               const hf4* __restrict__ gin,
                                               float* __restrict__ dummy) {
    __shared__ float acc[4][NPB];
    int tid = threadIdx.x, b = blockIdx.x;
    for (int k = tid; k < NPB; k += 1024) {
        acc[0][k] = 0.f; acc[1][k] = 0.f; acc[2][k] = 0.f; acc[3][k] = 0.f;
    }
    __syncthreads();
    int e0 = bbase[b], e1 = bbase[b + 1];
    for (int e = e0 + (tid << 3); e + 8 <= e1; e += 8192) {
        const int4* pp = (const int4*)(packed + e);
        int4 pa = pp[0], pb = pp[1];
        int ci = (e >> 3) & 65535;       // consecutive tids -> consecutive idx
        hf4 v0 = gin[ci];
        hf4 v1 = gin[ci ^ 1];
        hf4 v2 = gin[ci ^ 2];
        hf4 v3 = gin[ci ^ 3];
        hf4 v4 = gin[ci ^ 4];
        hf4 v5 = gin[ci ^ 5];
        hf4 v6 = gin[ci ^ 6];
        hf4 v7 = gin[ci ^ 7];
        ACC4(v0, pa.x & (NPB - 1)); ACC4(v1, pa.y & (NPB - 1));
        ACC4(v2, pa.z & (NPB - 1)); ACC4(v3, pa.w & (NPB - 1));
        ACC4(v4, pb.x & (NPB - 1)); ACC4(v5, pb.y & (NPB - 1));
        ACC4(v6, pb.z & (NPB - 1)); ACC4(v7, pb.w & (NPB - 1));
    }
    __syncthreads();
    float s = acc[0][tid & (NPB - 1)] + acc[3][(tid * 7) & (NPB - 1)];
    if (s + (float)tid == -987654.25f) dummy[b & 255] = s;
}

extern "C" void kernel_launch(void* const* d_in, const int* in_sizes, int n_in,
                              void* d_out, int out_size, void* d_ws, size_t ws_size,
                              hipStream_t stream) {
    const float* x  = (const float*)d_in[0];
    const int*   ei = (const int*)d_in[1];
    const float* W1 = (const float*)d_in[2];
    const float* b1 = (const float*)d_in[3];
    const float* W2 = (const float*)d_in[4];
    const float* b2 = (const float*)d_in[5];
    const float* W3 = (const float*)d_in[6];
    const float* b3 = (const float*)d_in[7];
    const float* Wc = (const float*)d_in[8];
    const float* bc = (const float*)d_in[9];

    const int n  = NN;
    const int ne = in_sizes[1] / 2;
    const int* src  = ei;
    const int* dstp = ei + ne;

    const int cap = ne + 8 * NBUCK;   // padded edge capacity

    char* base = (char*)d_ws;
    int*   packed = (int*)base;                       base += ((size_t)cap * 4 + 15) & ~15ull;
    float* dis    = (float*)base;                     base += (size_t)n * 4;
    hf4*   g1     = (hf4*)base;                       base += ((size_t)n + 1) * 8;
    hf4*   g2     = (hf4*)base;                       base += ((size_t)n + 1) * 8;
    hf2*   g3     = (hf2*)base;                       base += (((size_t)n + 1) * 4 + 15) & ~15ull;
    int*   bcount = (int*)base;                       base += (NBUCK + 1) * 4;
    int*   bbase  = (int*)base;                       base += (NBUCK + 1) * 4;
    int*   cur    = (int*)base;                       base += (NBUCK + 1) * 4;
    float* dummy  = (float*)base;                     // 1KB scratch for probes

    float4* out4  = (float4*)d_out;
    float2* hout2 = (float2*)((float*)d_out + 4 * (size_t)n);

    hipMemsetAsync(bcount, 0, (NBUCK + 1) * 4, stream);
    k_bhist<<<512, 256, 0, stream>>>(dstp, bcount, ne);
    k_bscan<<<1, 1024, 0, stream>>>(bcount, bbase, cur, g1, g2, g3);
    k_part<<<(ne + PT_TILE - 1) / PT_TILE, 256, 0, stream>>>(src, dstp, cur, packed, ne);
    k_pad<<<1, 1024, 0, stream>>>(cur, bbase, packed);
    k_deg<<<NBUCK, 1024, 0, stream>>>(bbase, packed, dis);
    k_xw<<<(n + 3) / 4, 256, 0, stream>>>(x, W1, dis, g1, n);
    k_agg44<<<NBUCK, 1024, 0, stream>>>(bbase, packed, g1, dis, b1, W2, g2);
    k_agg42<<<NBUCK, 1024, 0, stream>>>(bbase, packed, g2, dis, b2, W3, g3);
    k_agg2out<<<NBUCK, 1024, 0, stream>>>(bbase, packed, g3, dis, b3, Wc, bc,
                                          out4, hout2);

    // ---- ablation probes (outputs dead; timing/counters only) ----
    ab_gather<0><<<NBUCK, 1024, 0, stream>>>(bbase, packed, g1, dummy);
    ab_gather<1><<<NBUCK, 1024, 0, stream>>>(bbase, packed, g1, dummy);
    ab_lds<<<NBUCK, 1024, 0, stream>>>(bbase, packed, g1, dummy);
}

// Round 7
// 1331.612 us; speedup vs baseline: 1.4134x; 1.4134x over previous
//
#include <hip/hip_runtime.h>

#define NN 500000
#define SH 10
#define NPB 1024                          // nodes per dst-block (1 << SH)
#define NBUCK ((NN + NPB - 1) / NPB)      // 489
#define NSB 8                             // src slices (src >> 16 in 0..7)
#define NSEG (NBUCK * NSB)                // 3912
#define PT_TILE 65536                     // edges per partition block
#define SENT (NN << SH)                   // sentinel: src=NN, nd=0

typedef _Float16 hf4 __attribute__((ext_vector_type(4)));
typedef _Float16 hf2 __attribute__((ext_vector_type(2)));
typedef int i4v __attribute__((ext_vector_type(4)));

__device__ __forceinline__ i4v nt_load4(const int* p) {
    return __builtin_nontemporal_load((const i4v*)p);
}

// ============================================================================
// Bucketed GCN with (dst-block, src-slice) segmented edges:
//  agg blocks process src-slices in lockstep so the gather working set
//  (512KB table slice) stays L2-resident; packed stream read non-temporally.
// ============================================================================

// -------- per-(db,sb) histogram --------
__global__ __launch_bounds__(256) void k_bhist(const int* __restrict__ src,
                                               const int* __restrict__ dst,
                                               int* __restrict__ bcount, int ne) {
    __shared__ int lh[NSEG];
    for (int i = threadIdx.x; i < NSEG; i += 256) lh[i] = 0;
    __syncthreads();
    int ne4 = ne >> 2;
    for (int i = blockIdx.x * 256 + threadIdx.x; i < ne4; i += gridDim.x * 256) {
        int4 d = ((const int4*)dst)[i];
        int4 s = ((const int4*)src)[i];
        atomicAdd(&lh[(d.x >> SH) * NSB + ((unsigned)s.x >> 16)], 1);
        atomicAdd(&lh[(d.y >> SH) * NSB + ((unsigned)s.y >> 16)], 1);
        atomicAdd(&lh[(d.z >> SH) * NSB + ((unsigned)s.z >> 16)], 1);
        atomicAdd(&lh[(d.w >> SH) * NSB + ((unsigned)s.w >> 16)], 1);
    }
    if (blockIdx.x == 0) {
        for (int k = (ne & ~3) + threadIdx.x; k < ne; k += 256)
            atomicAdd(&lh[(dst[k] >> SH) * NSB + ((unsigned)src[k] >> 16)], 1);
    }
    __syncthreads();
    for (int i = threadIdx.x; i < NSEG; i += 256)
        if (lh[i]) atomicAdd(&bcount[i], lh[i]);
}

// -------- scan 3912 counts, each padded to x4; init cursors; zero g[NN] -----
__global__ __launch_bounds__(1024) void k_bscan(const int* __restrict__ bcount,
                                                int* __restrict__ bbase,
                                                int* __restrict__ cur,
                                                hf4* __restrict__ g1,
                                                hf4* __restrict__ g2,
                                                hf2* __restrict__ g3) {
    __shared__ int sh[1024];
    int t = threadIdx.x;
    int v0 = 0, v1 = 0, v2 = 0, v3 = 0;
    int i0 = t * 4;
    if (i0 + 0 < NSEG) v0 = (bcount[i0 + 0] + 3) & ~3;
    if (i0 + 1 < NSEG) v1 = (bcount[i0 + 1] + 3) & ~3;
    if (i0 + 2 < NSEG) v2 = (bcount[i0 + 2] + 3) & ~3;
    if (i0 + 3 < NSEG) v3 = (bcount[i0 + 3] + 3) & ~3;
    int tot = v0 + v1 + v2 + v3;
    sh[t] = tot;
    __syncthreads();
    for (int o = 1; o < 1024; o <<= 1) {
        int a = (t >= o) ? sh[t - o] : 0;
        __syncthreads();
        sh[t] += a;
        __syncthreads();
    }
    int o = sh[t] - tot;
    if (i0 + 0 < NSEG) { bbase[i0 + 0] = o; cur[i0 + 0] = o; o += v0; }
    if (i0 + 1 < NSEG) { bbase[i0 + 1] = o; cur[i0 + 1] = o; o += v1; }
    if (i0 + 2 < NSEG) { bbase[i0 + 2] = o; cur[i0 + 2] = o; o += v2; }
    if (i0 + 3 < NSEG) { bbase[i0 + 3] = o; cur[i0 + 3] = o; o += v3; }
    if (t == 1023) {
        bbase[NSEG] = sh[1023];
        hf4 z4; z4.x = z4.y = z4.z = z4.w = (_Float16)0.f;
        hf2 z2; z2.x = z2.y = (_Float16)0.f;
        g1[NN] = z4; g2[NN] = z4; g3[NN] = z2;
    }
}

// -------- partition edges into (db,sb) segments --------
__global__ __launch_bounds__(512) void k_part(const int* __restrict__ src,
                                              const int* __restrict__ dst,
                                              int* __restrict__ cur,
                                              int* __restrict__ packed, int ne) {
    __shared__ int lhist[NSEG];
    __shared__ int lcur[NSEG];
    int tid = threadIdx.x;
    for (int i = tid; i < NSEG; i += 512) lhist[i] = 0;
    __syncthreads();
    int t0 = blockIdx.x * PT_TILE;
    int t1 = t0 + PT_TILE; if (t1 > ne) t1 = ne;
    for (int e = t0 + tid * 4; e < t1; e += 2048) {
        if (e + 3 < t1) {
            int4 d = *(const int4*)(dst + e);
            int4 s = *(const int4*)(src + e);
            atomicAdd(&lhist[(d.x >> SH) * NSB + ((unsigned)s.x >> 16)], 1);
            atomicAdd(&lhist[(d.y >> SH) * NSB + ((unsigned)s.y >> 16)], 1);
            atomicAdd(&lhist[(d.z >> SH) * NSB + ((unsigned)s.z >> 16)], 1);
            atomicAdd(&lhist[(d.w >> SH) * NSB + ((unsigned)s.w >> 16)], 1);
        } else {
            for (int k = e; k < t1; ++k)
                atomicAdd(&lhist[(dst[k] >> SH) * NSB + ((unsigned)src[k] >> 16)], 1);
        }
    }
    __syncthreads();
    for (int i = tid; i < NSEG; i += 512) {
        int c = lhist[i];
        lcur[i] = c ? atomicAdd(&cur[i], c) : 0;
    }
    __syncthreads();
    for (int e = t0 + tid * 4; e < t1; e += 2048) {
        if (e + 3 < t1) {
            int4 d = *(const int4*)(dst + e);
            int4 s = *(const int4*)(src + e);
            int key, p;
            key = (d.x >> SH) * NSB + ((unsigned)s.x >> 16);
            p = atomicAdd(&lcur[key], 1); packed[p] = (s.x << SH) | (d.x & (NPB - 1));
            key = (d.y >> SH) * NSB + ((unsigned)s.y >> 16);
            p = atomicAdd(&lcur[key], 1); packed[p] = (s.y << SH) | (d.y & (NPB - 1));
            key = (d.z >> SH) * NSB + ((unsigned)s.z >> 16);
            p = atomicAdd(&lcur[key], 1); packed[p] = (s.z << SH) | (d.z & (NPB - 1));
            key = (d.w >> SH) * NSB + ((unsigned)s.w >> 16);
            p = atomicAdd(&lcur[key], 1); packed[p] = (s.w << SH) | (d.w & (NPB - 1));
        } else {
            for (int k = e; k < t1; ++k) {
                int dd = dst[k], ss = src[k];
                int key = (dd >> SH) * NSB + ((unsigned)ss >> 16);
                int p = atomicAdd(&lcur[key], 1);
                packed[p] = (ss << SH) | (dd & (NPB - 1));
            }
        }
    }
}

// -------- fill padding slots with SENT --------
__global__ __launch_bounds__(1024) void k_pad(const int* __restrict__ cur,
                                              const int* __restrict__ bbase,
                                              int* __restrict__ packed) {
    int s = blockIdx.x * 1024 + threadIdx.x;
    if (s < NSEG) {
        int e = cur[s], e1 = bbase[s + 1];
        for (; e < e1; ++e) packed[e] = SENT;
    }
}

// -------- degree --------
__global__ __launch_bounds__(1024) void k_deg(const int* __restrict__ bbase,
                                              const int* __restrict__ packed,
                                              float* __restrict__ dis) {
    __shared__ int cnt[NPB];
    int tid = threadIdx.x, b = blockIdx.x;
    cnt[tid] = 0;
    __syncthreads();
    int e0 = bbase[b * NSB], e1 = bbase[b * NSB + NSB];
    for (int e = e0 + (tid << 2); e < e1; e += 4096) {
        i4v p = nt_load4(packed + e);
        if (p.x != SENT) atomicAdd(&cnt[p.x & (NPB - 1)], 1);
        if (p.y != SENT) atomicAdd(&cnt[p.y & (NPB - 1)], 1);
        if (p.z != SENT) atomicAdd(&cnt[p.z & (NPB - 1)], 1);
        if (p.w != SENT) atomicAdd(&cnt[p.w & (NPB - 1)], 1);
    }
    __syncthreads();
    int i = (b << SH) + tid;
    if (i < NN) dis[i] = rsqrtf((float)cnt[tid] + 1.0f);
}

// -------- g1 = half4( dis * (x @ W1) ), wave per row --------
__global__ __launch_bounds__(256) void k_xw(const float* __restrict__ x,
                                            const float* __restrict__ W1,
                                            const float* __restrict__ dis,
                                            hf4* __restrict__ g, int n) {
    __shared__ float4 sW[128];
    int tid = threadIdx.x;
    if (tid < 128) sW[tid] = ((const float4*)W1)[tid];
    __syncthreads();
    int wave = tid >> 6, lane = tid & 63;
    int row = blockIdx.x * 4 + wave;
    if (row >= n) return;
    float2 xv = ((const float2*)(x + (size_t)row * 128))[lane];
    float4 w0 = sW[2 * lane], w1 = sW[2 * lane + 1];
    float a0 = xv.x * w0.x + xv.y * w1.x;
    float a1 = xv.x * w0.y + xv.y * w1.y;
    float a2 = xv.x * w0.z + xv.y * w1.z;
    float a3 = xv.x * w0.w + xv.y * w1.w;
    for (int off = 32; off; off >>= 1) {
        a0 += __shfl_xor(a0, off);
        a1 += __shfl_xor(a1, off);
        a2 += __shfl_xor(a2, off);
        a3 += __shfl_xor(a3, off);
    }
    if (lane == 0) {
        float dv = dis[row];
        hf4 o;
        o.x = (_Float16)(dv * a0); o.y = (_Float16)(dv * a1);
        o.z = (_Float16)(dv * a2); o.w = (_Float16)(dv * a3);
        g[row] = o;
    }
}

#define ACC4(v, nd)                                   \
    unsafeAtomicAdd(&acc[0][nd], (float)(v).x);       \
    unsafeAtomicAdd(&acc[1][nd], (float)(v).y);       \
    unsafeAtomicAdd(&acc[2][nd], (float)(v).z);       \
    unsafeAtomicAdd(&acc[3][nd], (float)(v).w);

// -------- layer: gin hf4 -> gout hf4 via W (4x4), bias --------
__global__ __launch_bounds__(1024) void k_agg44(const int* __restrict__ bbase,
                                                const int* __restrict__ packed,
                                                const hf4* __restrict__ gin,
                                                const float* __restrict__ dis,
                                                const float* __restrict__ bias,
                                                const float* __restrict__ W,
                                                hf4* __restrict__ gout) {
    __shared__ float acc[4][NPB];
    int tid = threadIdx.x, b = blockIdx.x;
    acc[0][tid] = 0.f; acc[1][tid] = 0.f; acc[2][tid] = 0.f; acc[3][tid] = 0.f;
    __syncthreads();
    for (int s = b * NSB; s < b * NSB + NSB; ++s) {
        int s0 = bbase[s], s1 = bbase[s + 1];
        for (int e = s0 + (tid << 2); e < s1; e += 4096) {
            i4v p = nt_load4(packed + e);
            hf4 v0 = gin[(unsigned)p.x >> SH];
            hf4 v1 = gin[(unsigned)p.y >> SH];
            hf4 v2 = gin[(unsigned)p.z >> SH];
            hf4 v3 = gin[(unsigned)p.w >> SH];
            ACC4(v0, p.x & (NPB - 1));
            ACC4(v1, p.y & (NPB - 1));
            ACC4(v2, p.z & (NPB - 1));
            ACC4(v3, p.w & (NPB - 1));
        }
        __syncthreads();   // keep all blocks' waves on the same src slice
    }
    int i = (b << SH) + tid;
    if (i >= NN) return;
    float dv = dis[i];
    hf4 gs = gin[i];
    float h0 = tanhf(dv * (acc[0][tid] + (float)gs.x) + bias[0]);
    float h1 = tanhf(dv * (acc[1][tid] + (float)gs.y) + bias[1]);
    float h2 = tanhf(dv * (acc[2][tid] + (float)gs.z) + bias[2]);
    float h3 = tanhf(dv * (acc[3][tid] + (float)gs.w) + bias[3]);
    hf4 o;
    o.x = (_Float16)(dv * (h0 * W[0] + h1 * W[4] + h2 * W[8]  + h3 * W[12]));
    o.y = (_Float16)(dv * (h0 * W[1] + h1 * W[5] + h2 * W[9]  + h3 * W[13]));
    o.z = (_Float16)(dv * (h0 * W[2] + h1 * W[6] + h2 * W[10] + h3 * W[14]));
    o.w = (_Float16)(dv * (h0 * W[3] + h1 * W[7] + h2 * W[11] + h3 * W[15]));
    gout[i] = o;
}

// -------- layer: gin hf4 -> gout hf2 via W (4x2), bias --------
__global__ __launch_bounds__(1024) void k_agg42(const int* __restrict__ bbase,
                                                const int* __restrict__ packed,
                                                const hf4* __restrict__ gin,
                                                const float* __restrict__ dis,
                                                const float* __restrict__ bias,
                                                const float* __restrict__ W,
                                                hf2* __restrict__ gout) {
    __shared__ float acc[4][NPB];
    int tid = threadIdx.x, b = blockIdx.x;
    acc[0][tid] = 0.f; acc[1][tid] = 0.f; acc[2][tid] = 0.f; acc[3][tid] = 0.f;
    __syncthreads();
    for (int s = b * NSB; s < b * NSB + NSB; ++s) {
        int s0 = bbase[s], s1 = bbase[s + 1];
        for (int e = s0 + (tid << 2); e < s1; e += 4096) {
            i4v p = nt_load4(packed + e);
            hf4 v0 = gin[(unsigned)p.x >> SH];
            hf4 v1 = gin[(unsigned)p.y >> SH];
            hf4 v2 = gin[(unsigned)p.z >> SH];
            hf4 v3 = gin[(unsigned)p.w >> SH];
            ACC4(v0, p.x & (NPB - 1));
            ACC4(v1, p.y & (NPB - 1));
            ACC4(v2, p.z & (NPB - 1));
            ACC4(v3, p.w & (NPB - 1));
        }
        __syncthreads();
    }
    int i = (b << SH) + tid;
    if (i >= NN) return;
    float dv = dis[i];
    hf4 gs = gin[i];
    float h0 = tanhf(dv * (acc[0][tid] + (float)gs.x) + bias[0]);
    float h1 = tanhf(dv * (acc[1][tid] + (float)gs.y) + bias[1]);
    float h2 = tanhf(dv * (acc[2][tid] + (float)gs.z) + bias[2]);
    float h3 = tanhf(dv * (acc[3][tid] + (float)gs.w) + bias[3]);
    hf2 o;
    o.x = (_Float16)(dv * (h0 * W[0] + h1 * W[2] + h2 * W[4] + h3 * W[6]));
    o.y = (_Float16)(dv * (h0 * W[1] + h1 * W[3] + h2 * W[5] + h3 * W[7]));
    gout[i] = o;
}

// -------- final layer + classifier --------
__global__ __launch_bounds__(1024) void k_agg2out(const int* __restrict__ bbase,
                                                  const int* __restrict__ packed,
                                                  const hf2* __restrict__ gin,
                                                  const float* __restrict__ dis,
                                                  const float* __restrict__ b3,
                                                  const float* __restrict__ Wc,
                                                  const float* __restrict__ bc,
                                                  float4* __restrict__ out,
                                                  float2* __restrict__ hout) {
    __shared__ float acc[2][NPB];
    int tid = threadIdx.x, b = blockIdx.x;
    acc[0][tid] = 0.f; acc[1][tid] = 0.f;
    __syncthreads();
    for (int s = b * NSB; s < b * NSB + NSB; ++s) {
        int s0 = bbase[s], s1 = bbase[s + 1];
        for (int e = s0 + (tid << 2); e < s1; e += 4096) {
            i4v p = nt_load4(packed + e);
            hf2 v0 = gin[(unsigned)p.x >> SH];
            hf2 v1 = gin[(unsigned)p.y >> SH];
            hf2 v2 = gin[(unsigned)p.z >> SH];
            hf2 v3 = gin[(unsigned)p.w >> SH];
            int nd;
            nd = p.x & (NPB - 1);
            unsafeAtomicAdd(&acc[0][nd], (float)v0.x); unsafeAtomicAdd(&acc[1][nd], (float)v0.y);
            nd = p.y & (NPB - 1);
            unsafeAtomicAdd(&acc[0][nd], (float)v1.x); unsafeAtomicAdd(&acc[1][nd], (float)v1.y);
            nd = p.z & (NPB - 1);
            unsafeAtomicAdd(&acc[0][nd], (float)v2.x); unsafeAtomicAdd(&acc[1][nd], (float)v2.y);
            nd = p.w & (NPB - 1);
            unsafeAtomicAdd(&acc[0][nd], (float)v3.x); unsafeAtomicAdd(&acc[1][nd], (float)v3.y);
        }
        __syncthreads();
    }
    int i = (b << SH) + tid;
    if (i >= NN) return;
    float dv = dis[i];
    hf2 gs = gin[i];
    float h0 = tanhf(dv * (acc[0][tid] + (float)gs.x) + b3[0]);
    float h1 = tanhf(dv * (acc[1][tid] + (float)gs.y) + b3[1]);
    float4 o;
    o.x = h0 * Wc[0] + h1 * Wc[4] + bc[0];
    o.y = h0 * Wc[1] + h1 * Wc[5] + bc[1];
    o.z = h0 * Wc[2] + h1 * Wc[6] + bc[2];
    o.w = h0 * Wc[3] + h1 * Wc[7] + bc[3];
    out[i] = o;
    hout[i] = make_float2(h0, h1);
}

extern "C" void kernel_launch(void* const* d_in, const int* in_sizes, int n_in,
                              void* d_out, int out_size, void* d_ws, size_t ws_size,
                              hipStream_t stream) {
    const float* x  = (const float*)d_in[0];
    const int*   ei = (const int*)d_in[1];
    const float* W1 = (const float*)d_in[2];
    const float* b1 = (const float*)d_in[3];
    const float* W2 = (const float*)d_in[4];
    const float* b2 = (const float*)d_in[5];
    const float* W3 = (const float*)d_in[6];
    const float* b3 = (const float*)d_in[7];
    const float* Wc = (const float*)d_in[8];
    const float* bc = (const float*)d_in[9];

    const int n  = NN;
    const int ne = in_sizes[1] / 2;
    const int* src  = ei;
    const int* dstp = ei + ne;

    const int cap = ne + 4 * NSEG;   // padded edge capacity

    char* base = (char*)d_ws;
    int*   packed = (int*)base;                       base += ((size_t)cap * 4 + 15) & ~15ull;
    float* dis    = (float*)base;                     base += (size_t)n * 4;
    hf4*   g1     = (hf4*)base;                       base += ((size_t)n + 1) * 8;
    hf4*   g2     = (hf4*)base;                       base += ((size_t)n + 1) * 8;
    hf2*   g3     = (hf2*)base;                       base += (((size_t)n + 1) * 4 + 15) & ~15ull;
    int*   bcount = (int*)base;                       base += (NSEG + 1) * 4;
    int*   bbase  = (int*)base;                       base += (NSEG + 1) * 4;
    int*   cur    = (int*)base;

    float4* out4  = (float4*)d_out;
    float2* hout2 = (float2*)((float*)d_out + 4 * (size_t)n);

    hipMemsetAsync(bcount, 0, (NSEG + 1) * 4, stream);
    k_bhist<<<128, 256, 0, stream>>>(src, dstp, bcount, ne);
    k_bscan<<<1, 1024, 0, stream>>>(bcount, bbase, cur, g1, g2, g3);
    k_part<<<(ne + PT_TILE - 1) / PT_TILE, 512, 0, stream>>>(src, dstp, cur, packed, ne);
    k_pad<<<(NSEG + 1023) / 1024, 1024, 0, stream>>>(cur, bbase, packed);
    k_deg<<<NBUCK, 1024, 0, stream>>>(bbase, packed, dis);
    k_xw<<<(n + 3) / 4, 256, 0, stream>>>(x, W1, dis, g1, n);
    k_agg44<<<NBUCK, 1024, 0, stream>>>(bbase, packed, g1, dis, b1, W2, g2);
    k_agg42<<<NBUCK, 1024, 0, stream>>>(bbase, packed, g2, dis, b2, W3, g3);
    k_agg2out<<<NBUCK, 1024, 0, stream>>>(bbase, packed, g3, dis, b3, Wc, bc,
                                          out4, hout2);
}